// Round 3
// baseline (716.535 us; speedup 1.0000x reference)
//
#include <hip/hip_runtime.h>
#include <hip/hip_bf16.h>

#define H 1024
#define F 4096
#define NE 8
#define T 4096
// split-K factor for gemm2: K=4096 -> 2 chunks of 2048.
#define KSPLIT2 2

typedef unsigned short u16;
typedef float floatx4 __attribute__((ext_vector_type(4)));
typedef short short8 __attribute__((ext_vector_type(8)));

__device__ __forceinline__ u16 f2bf(float f) {
  union { float f; unsigned int u; } c; c.f = f;
  unsigned int u = c.u;
  return (u16)((u + 0x7fffu + ((u >> 16) & 1u)) >> 16);
}

// async global->LDS, 16B per lane. LDS dest must be uniform base + lane*16.
__device__ __forceinline__ void load16_lds(const u16* g, u16* l) {
  __builtin_amdgcn_global_load_lds(
      (const __attribute__((address_space(1))) unsigned int*)g,
      (__attribute__((address_space(3))) unsigned int*)l, 16, 0, 0);
}

// exact-enough GELU: erf via Abramowitz-Stegun 7.1.26, |err|<1.5e-7 —
// 4 orders below the bf16 quantum Hc is rounded to.
__device__ __forceinline__ float gelu_f(float v) {
  float y = fabsf(v) * 0.70710678118f;
  float t = __builtin_amdgcn_rcpf(fmaf(0.3275911f, y, 1.0f));
  float p = t * fmaf(t, fmaf(t, fmaf(t, fmaf(t, 1.061405429f, -1.453152027f),
                                     1.421413741f), -0.284496736f), 0.254829592f);
  float e = __builtin_amdgcn_exp2f(-y * y * 1.44269504f);
  float erfv = fmaf(-p, e, 1.0f);          // erf(|v|/sqrt2)
  return fmaf(0.5f * fabsf(v), erfv, 0.5f * v);  // 0.5v(1+sign(v)erf)
}

// ---------------- router: one wave per token, fp64 logits ----------------
__global__ __launch_bounds__(256) void router_kernel(
    const float* __restrict__ x, const float* __restrict__ Wr,
    int* __restrict__ cnt, int* __restrict__ tok, float* __restrict__ wgt) {
  int t = (blockIdx.x * 256 + threadIdx.x) >> 6;
  int lane = threadIdx.x & 63;
  const float* xr = x + (size_t)t * H;
  double p[NE];
#pragma unroll
  for (int e = 0; e < NE; ++e) p[e] = 0.0;
  for (int k = lane; k < H; k += 64) {
    float xv = xr[k];
    const float4* wr4 = reinterpret_cast<const float4*>(Wr + k * NE);
    float4 a = wr4[0], b = wr4[1];
    p[0] += (double)xv * a.x; p[1] += (double)xv * a.y;
    p[2] += (double)xv * a.z; p[3] += (double)xv * a.w;
    p[4] += (double)xv * b.x; p[5] += (double)xv * b.y;
    p[6] += (double)xv * b.z; p[7] += (double)xv * b.w;
  }
#pragma unroll
  for (int e = 0; e < NE; ++e) {
#pragma unroll
    for (int off = 32; off; off >>= 1) p[e] += __shfl_down(p[e], off, 64);
  }
  if (lane == 0) {
    int i0 = 0;
#pragma unroll
    for (int e = 1; e < NE; ++e) if (p[e] > p[i0]) i0 = e;
    int i1 = (i0 == 0) ? 1 : 0;
#pragma unroll
    for (int e = 0; e < NE; ++e) if (e != i0 && p[e] > p[i1]) i1 = e;
    double d = exp(p[i1] - p[i0]);
    float w0 = (float)(1.0 / (1.0 + d));
    float w1 = (float)(d / (1.0 + d));
    int pos0 = atomicAdd(&cnt[i0], 1);
    tok[i0 * T + pos0] = t; wgt[i0 * T + pos0] = w0;
    int pos1 = atomicAdd(&cnt[i1], 1);
    tok[i1 * T + pos1] = t; wgt[i1 * T + pos1] = w1;
  }
}

__global__ void offsets_kernel(const int* __restrict__ cnt, int* __restrict__ off) {
  if (threadIdx.x == 0) {
    int s = 0;
#pragma unroll
    for (int e = 0; e < NE; ++e) { off[e] = s; s += cnt[e]; }
    off[NE] = s;
  }
}

// ---------------- x -> bf16 ----------------
__global__ __launch_bounds__(256) void convert_x_kernel(
    const float* __restrict__ x, u16* __restrict__ xb) {
  int i = blockIdx.x * 256 + threadIdx.x;
  float4 v = reinterpret_cast<const float4*>(x)[i];
  ushort4 o;
  o.x = f2bf(v.x); o.y = f2bf(v.y); o.z = f2bf(v.z); o.w = f2bf(v.w);
  reinterpret_cast<ushort4*>(xb)[i] = o;
}

// ---- fused weight transpose: [E][R][C] f32 -> [E][C][R] bf16, both W1,W2 ----
// grid (64, 16, 16): z<8 -> W1 (R=H,C=F, c-tile=x, r-tile=y),
//                    z>=8 -> W2 (R=F,C=H, c-tile=y, r-tile=x).
__global__ __launch_bounds__(256) void transpose_both_kernel(
    const float* __restrict__ W1, const float* __restrict__ W2,
    u16* __restrict__ W1t, u16* __restrict__ W2t) {
  __shared__ u16 tile[64][72];
  int z = blockIdx.z;
  int e = z & 7;
  const float* s; u16* d; int R, C, c0, r0;
  if (z < NE) {
    s = W1 + (size_t)e * H * F; d = W1t + (size_t)e * H * F;
    R = H; C = F; c0 = blockIdx.x << 6; r0 = blockIdx.y << 6;
  } else {
    s = W2 + (size_t)e * F * H; d = W2t + (size_t)e * F * H;
    R = F; C = H; c0 = blockIdx.y << 6; r0 = blockIdx.x << 6;
  }
  int t = threadIdx.x;
  int rl = t >> 4, cl = (t & 15) << 2;
#pragma unroll
  for (int i = 0; i < 4; ++i) {
    float4 v = *reinterpret_cast<const float4*>(&s[(size_t)(r0 + rl + i * 16) * C + c0 + cl]);
    ushort4 o; o.x = f2bf(v.x); o.y = f2bf(v.y); o.z = f2bf(v.z); o.w = f2bf(v.w);
    *reinterpret_cast<ushort4*>(&tile[rl + i * 16][cl]) = o;
  }
  __syncthreads();
  int cl2 = t >> 4, rl2 = (t & 15) << 2;
#pragma unroll
  for (int i = 0; i < 4; ++i) {
    ushort4 o;
    o.x = tile[rl2 + 0][cl2 + i * 16];
    o.y = tile[rl2 + 1][cl2 + i * 16];
    o.z = tile[rl2 + 2][cl2 + i * 16];
    o.w = tile[rl2 + 3][cl2 + i * 16];
    *reinterpret_cast<ushort4*>(&d[(size_t)(c0 + cl2 + i * 16) * R + r0 + rl2]) = o;
  }
}

// ---------------- GEMM1: Hc = gelu(gather(Xb) @ W1t^T + b1) ----------------
// grid: (F/128, 32 m-tiles, NE). 256 thr = 4 waves (2x2 of 64x64).
// 3-buffer depth-2 pipeline: counted vmcnt(4) + raw s_barrier per K-step —
// loads stay in flight across 2 iterations (never drain to 0 in the loop).
__global__ __launch_bounds__(256) void gemm1_kernel(
    const u16* __restrict__ Xb, const u16* __restrict__ W1t,
    const float* __restrict__ b1, const int* __restrict__ cnt,
    const int* __restrict__ off, const int* __restrict__ tok,
    u16* __restrict__ Hc) {
  int e = blockIdx.z;
  int n = cnt[e];
  int m0 = blockIdx.y << 7;
  if (m0 >= n) return;
  int n0 = blockIdx.x << 7;
  int rb = off[e];

  __shared__ alignas(16) u16 As[3][128 * 32];
  __shared__ alignas(16) u16 Bs[3][128 * 32];
  __shared__ int tokS[128];

  int tid = threadIdx.x;
  if (tid < 128) {
    int s = m0 + tid;
    tokS[tid] = (s < n) ? tok[e * T + s] : 0;
  }
  __syncthreads();

  const u16* W1e = W1t + (size_t)e * F * H;
  const u16* aP0 = Xb + (size_t)tokS[tid >> 2] * H + (tid & 3) * 8;
  const u16* aP1 = Xb + (size_t)tokS[64 + (tid >> 2)] * H + (tid & 3) * 8;
  const u16* bP0 = W1e + (size_t)(n0 + (tid >> 2)) * H + (tid & 3) * 8;
  const u16* bP1 = W1e + (size_t)(n0 + 64 + (tid >> 2)) * H + (tid & 3) * 8;

  int wv = tid >> 6, lane = tid & 63;
  int wm = wv >> 1, wn = wv & 1;
  int quad = lane >> 4, l16 = lane & 15;

  floatx4 acc[4][4];
#pragma unroll
  for (int mt = 0; mt < 4; ++mt)
#pragma unroll
    for (int nt = 0; nt < 4; ++nt) acc[mt][nt] = floatx4{0.f, 0.f, 0.f, 0.f};

  int aOff[4], bOff[4];
#pragma unroll
  for (int i = 0; i < 4; ++i) {
    aOff[i] = (wm * 64 + i * 16 + l16) * 32 + quad * 8;
    bOff[i] = (wn * 64 + i * 16 + l16) * 32 + quad * 8;
  }

#define STAGE1(buf, kk)                                   \
  do {                                                    \
    load16_lds(aP0 + (kk), &As[buf][tid * 8]);            \
    load16_lds(aP1 + (kk), &As[buf][(tid + 256) * 8]);    \
    load16_lds(bP0 + (kk), &Bs[buf][tid * 8]);            \
    load16_lds(bP1 + (kk), &Bs[buf][(tid + 256) * 8]);    \
  } while (0)

  const int NIT = H / 32;  // 32
  STAGE1(0, 0);
  STAGE1(1, 32);
  for (int it = 0; it < NIT; ++it) {
    // wait for buf it%3's 4 loads: everything except the most recent stage (4)
    if (it == NIT - 1) asm volatile("s_waitcnt vmcnt(0)" ::: "memory");
    else               asm volatile("s_waitcnt vmcnt(4)" ::: "memory");
    __builtin_amdgcn_s_barrier();
    int cur = it % 3;
    if (it + 2 < NIT) STAGE1((it + 2) % 3, (it + 2) * 32);
    short8 av[4], bv[4];
#pragma unroll
    for (int i = 0; i < 4; ++i) {
      av[i] = *reinterpret_cast<const short8*>(&As[cur][aOff[i]]);
      bv[i] = *reinterpret_cast<const short8*>(&Bs[cur][bOff[i]]);
    }
#pragma unroll
    for (int mt = 0; mt < 4; ++mt)
#pragma unroll
      for (int nt = 0; nt < 4; ++nt)
        acc[mt][nt] = __builtin_amdgcn_mfma_f32_16x16x32_bf16(av[mt], bv[nt], acc[mt][nt], 0, 0, 0);
  }
#undef STAGE1

  // epilogue: bias + gelu -> bf16 -> Hc[rb + row][col]
  float b1v[4];
#pragma unroll
  for (int nt = 0; nt < 4; ++nt)
    b1v[nt] = b1[e * F + n0 + wn * 64 + nt * 16 + l16];
#pragma unroll
  for (int mt = 0; mt < 4; ++mt) {
#pragma unroll
    for (int i = 0; i < 4; ++i) {
      int row = wm * 64 + mt * 16 + quad * 4 + i;
      int gr = m0 + row;
      if (gr < n) {
        u16* hrow = Hc + (size_t)(rb + gr) * F + n0 + wn * 64 + l16;
#pragma unroll
        for (int nt = 0; nt < 4; ++nt) {
          float v = acc[mt][nt][i] + b1v[nt];
          hrow[nt * 16] = f2bf(gelu_f(v));
        }
      }
    }
  }
}

// ---------------- GEMM2: out += w * (Hc @ W2t^T + b2) ----------------
// grid: (H/128, 32 m-tiles, NE*KSPLIT2). Same 3-buffer depth-2 pipeline.
__global__ __launch_bounds__(256) void gemm2_kernel(
    const u16* __restrict__ Hc, const u16* __restrict__ W2t,
    const float* __restrict__ b2, const int* __restrict__ cnt,
    const int* __restrict__ off, const int* __restrict__ tok,
    const float* __restrict__ wgt, float* __restrict__ out) {
  int e = blockIdx.z >> 1;          // KSPLIT2 == 2
  int kc = blockIdx.z & 1;
  int n = cnt[e];
  int m0 = blockIdx.y << 7;
  if (m0 >= n) return;
  int n0 = blockIdx.x << 7;
  int rb = off[e];

  __shared__ alignas(16) u16 As[3][128 * 32];
  __shared__ alignas(16) u16 Bs[3][128 * 32];

  int tid = threadIdx.x;
  const u16* W2e = W2t + (size_t)e * F * H;
  const u16* aP0 = Hc + (size_t)(rb + m0 + (tid >> 2)) * F + (tid & 3) * 8;
  const u16* aP1 = Hc + (size_t)(rb + m0 + 64 + (tid >> 2)) * F + (tid & 3) * 8;
  const u16* bP0 = W2e + (size_t)(n0 + (tid >> 2)) * F + (tid & 3) * 8;
  const u16* bP1 = W2e + (size_t)(n0 + 64 + (tid >> 2)) * F + (tid & 3) * 8;

  int wv = tid >> 6, lane = tid & 63;
  int wm = wv >> 1, wn = wv & 1;
  int quad = lane >> 4, l16 = lane & 15;

  floatx4 acc[4][4];
#pragma unroll
  for (int mt = 0; mt < 4; ++mt)
#pragma unroll
    for (int nt = 0; nt < 4; ++nt) acc[mt][nt] = floatx4{0.f, 0.f, 0.f, 0.f};

  int aOff[4], bOff[4];
#pragma unroll
  for (int i = 0; i < 4; ++i) {
    aOff[i] = (wm * 64 + i * 16 + l16) * 32 + quad * 8;
    bOff[i] = (wn * 64 + i * 16 + l16) * 32 + quad * 8;
  }

#define STAGE2(buf, kk)                                   \
  do {                                                    \
    load16_lds(aP0 + (kk), &As[buf][tid * 8]);            \
    load16_lds(aP1 + (kk), &As[buf][(tid + 256) * 8]);    \
    load16_lds(bP0 + (kk), &Bs[buf][tid * 8]);            \
    load16_lds(bP1 + (kk), &Bs[buf][(tid + 256) * 8]);    \
  } while (0)

  const int kBeg = kc * (F / KSPLIT2);
  const int NIT = (F / KSPLIT2) / 32;  // 64
  STAGE2(0, kBeg);
  STAGE2(1, kBeg + 32);
  for (int it = 0; it < NIT; ++it) {
    if (it == NIT - 1) asm volatile("s_waitcnt vmcnt(0)" ::: "memory");
    else               asm volatile("s_waitcnt vmcnt(4)" ::: "memory");
    __builtin_amdgcn_s_barrier();
    int cur = it % 3;
    if (it + 2 < NIT) STAGE2((it + 2) % 3, kBeg + (it + 2) * 32);
    short8 av[4], bv[4];
#pragma unroll
    for (int i = 0; i < 4; ++i) {
      av[i] = *reinterpret_cast<const short8*>(&As[cur][aOff[i]]);
      bv[i] = *reinterpret_cast<const short8*>(&Bs[cur][bOff[i]]);
    }
#pragma unroll
    for (int mt = 0; mt < 4; ++mt)
#pragma unroll
      for (int nt = 0; nt < 4; ++nt)
        acc[mt][nt] = __builtin_amdgcn_mfma_f32_16x16x32_bf16(av[mt], bv[nt], acc[mt][nt], 0, 0, 0);
  }
#undef STAGE2

  float b2v[4];
#pragma unroll
  for (int nt = 0; nt < 4; ++nt)
    b2v[nt] = (kc == 0) ? b2[e * H + n0 + wn * 64 + nt * 16 + l16] : 0.0f;
#pragma unroll
  for (int mt = 0; mt < 4; ++mt) {
#pragma unroll
    for (int i = 0; i < 4; ++i) {
      int row = wm * 64 + mt * 16 + quad * 4 + i;
      int gr = m0 + row;
      if (gr < n) {
        float wv2 = wgt[e * T + gr];
        int tk = tok[e * T + gr];
        float* orow = out + (size_t)tk * H + n0 + wn * 64 + l16;
#pragma unroll
        for (int nt = 0; nt < 4; ++nt)
          atomicAdd(orow + nt * 16, (acc[mt][nt][i] + b2v[nt]) * wv2);
      }
    }
  }
}

extern "C" void kernel_launch(void* const* d_in, const int* in_sizes, int n_in,
                              void* d_out, int out_size, void* d_ws, size_t ws_size,
                              hipStream_t stream) {
  const float* x  = (const float*)d_in[0];
  const float* Wr = (const float*)d_in[1];
  const float* W1 = (const float*)d_in[2];
  const float* b1 = (const float*)d_in[3];
  const float* W2 = (const float*)d_in[4];
  const float* b2 = (const float*)d_in[5];
  float* out = (float*)d_out;

  char* ws = (char*)d_ws;
  // cnt@0 off@256 tok@4096(128K) wgt@135168(128K) Xb@266240(8M)
  // W1t@8654848(64M) W2t@75763712(64M) Hc@142872576(65M+slack) -> ~201MB total
  int*   cnt = (int*)(ws + 0);
  int*   off = (int*)(ws + 256);
  int*   tok = (int*)(ws + 4096);
  float* wgt = (float*)(ws + 135168);
  u16*   Xb  = (u16*)(ws + 266240);
  u16*   W1t = (u16*)(ws + 8654848);
  u16*   W2t = (u16*)(ws + 75763712);
  u16*   Hc  = (u16*)(ws + 142872576);

  hipMemsetAsync(cnt, 0, 64, stream);
  hipMemsetAsync(out, 0, (size_t)out_size * sizeof(float), stream);

  router_kernel<<<dim3(T / 4), dim3(256), 0, stream>>>(x, Wr, cnt, tok, wgt);
  offsets_kernel<<<dim3(1), dim3(64), 0, stream>>>(cnt, off);
  convert_x_kernel<<<dim3((T * H / 4) / 256), dim3(256), 0, stream>>>(x, Xb);
  transpose_both_kernel<<<dim3(64, 16, 16), dim3(256), 0, stream>>>(W1, W2, W1t, W2t);
  gemm1_kernel<<<dim3(F / 128, 32, NE), dim3(256), 0, stream>>>(Xb, W1t, b1, cnt, off, tok, Hc);
  gemm2_kernel<<<dim3(H / 128, 32, NE * KSPLIT2), dim3(256), 0, stream>>>(Hc, W2t, b2, cnt, off, tok, wgt, out);
}

// Round 4
// 676.181 us; speedup vs baseline: 1.0597x; 1.0597x over previous
//
#include <hip/hip_runtime.h>
#include <hip/hip_bf16.h>

#define H 1024
#define F 4096
#define NE 8
#define T 4096
// split-K factor for gemm2: K=4096 -> 2 chunks of 2048.
#define KSPLIT2 2

typedef unsigned short u16;
typedef float floatx4 __attribute__((ext_vector_type(4)));
typedef short short8 __attribute__((ext_vector_type(8)));

__device__ __forceinline__ u16 f2bf(float f) {
  union { float f; unsigned int u; } c; c.f = f;
  unsigned int u = c.u;
  return (u16)((u + 0x7fffu + ((u >> 16) & 1u)) >> 16);
}

// async global->LDS, 16B per lane. LDS dest must be uniform base + lane*16.
__device__ __forceinline__ void load16_lds(const u16* g, u16* l) {
  __builtin_amdgcn_global_load_lds(
      (const __attribute__((address_space(1))) unsigned int*)g,
      (__attribute__((address_space(3))) unsigned int*)l, 16, 0, 0);
}

// exact-enough GELU: erf via Abramowitz-Stegun 7.1.26, |err|<1.5e-7 —
// 4 orders below the bf16 quantum Hc is rounded to.
__device__ __forceinline__ float gelu_f(float v) {
  float y = fabsf(v) * 0.70710678118f;
  float t = __builtin_amdgcn_rcpf(fmaf(0.3275911f, y, 1.0f));
  float p = t * fmaf(t, fmaf(t, fmaf(t, fmaf(t, 1.061405429f, -1.453152027f),
                                     1.421413741f), -0.284496736f), 0.254829592f);
  float e = __builtin_amdgcn_exp2f(-y * y * 1.44269504f);
  float erfv = fmaf(-p, e, 1.0f);          // erf(|v|/sqrt2)
  return fmaf(0.5f * fabsf(v), erfv, 0.5f * v);  // 0.5v(1+sign(v)erf)
}

// ---------------- router: one wave per token, fp64 logits ----------------
__global__ __launch_bounds__(256) void router_kernel(
    const float* __restrict__ x, const float* __restrict__ Wr,
    int* __restrict__ cnt, int* __restrict__ tok, float* __restrict__ wgt) {
  int t = (blockIdx.x * 256 + threadIdx.x) >> 6;
  int lane = threadIdx.x & 63;
  const float* xr = x + (size_t)t * H;
  double p[NE];
#pragma unroll
  for (int e = 0; e < NE; ++e) p[e] = 0.0;
  for (int k = lane; k < H; k += 64) {
    float xv = xr[k];
    const float4* wr4 = reinterpret_cast<const float4*>(Wr + k * NE);
    float4 a = wr4[0], b = wr4[1];
    p[0] += (double)xv * a.x; p[1] += (double)xv * a.y;
    p[2] += (double)xv * a.z; p[3] += (double)xv * a.w;
    p[4] += (double)xv * b.x; p[5] += (double)xv * b.y;
    p[6] += (double)xv * b.z; p[7] += (double)xv * b.w;
  }
#pragma unroll
  for (int e = 0; e < NE; ++e) {
#pragma unroll
    for (int off = 32; off; off >>= 1) p[e] += __shfl_down(p[e], off, 64);
  }
  if (lane == 0) {
    int i0 = 0;
#pragma unroll
    for (int e = 1; e < NE; ++e) if (p[e] > p[i0]) i0 = e;
    int i1 = (i0 == 0) ? 1 : 0;
#pragma unroll
    for (int e = 0; e < NE; ++e) if (e != i0 && p[e] > p[i1]) i1 = e;
    double d = exp(p[i1] - p[i0]);
    float w0 = (float)(1.0 / (1.0 + d));
    float w1 = (float)(d / (1.0 + d));
    int pos0 = atomicAdd(&cnt[i0], 1);
    tok[i0 * T + pos0] = t; wgt[i0 * T + pos0] = w0;
    int pos1 = atomicAdd(&cnt[i1], 1);
    tok[i1 * T + pos1] = t; wgt[i1 * T + pos1] = w1;
  }
}

__global__ void offsets_kernel(const int* __restrict__ cnt, int* __restrict__ off) {
  if (threadIdx.x == 0) {
    int s = 0;
#pragma unroll
    for (int e = 0; e < NE; ++e) { off[e] = s; s += cnt[e]; }
    off[NE] = s;
  }
}

// ---------------- x -> bf16 ----------------
__global__ __launch_bounds__(256) void convert_x_kernel(
    const float* __restrict__ x, u16* __restrict__ xb) {
  int i = blockIdx.x * 256 + threadIdx.x;
  float4 v = reinterpret_cast<const float4*>(x)[i];
  ushort4 o;
  o.x = f2bf(v.x); o.y = f2bf(v.y); o.z = f2bf(v.z); o.w = f2bf(v.w);
  reinterpret_cast<ushort4*>(xb)[i] = o;
}

// ---- fused weight transpose: [E][R][C] f32 -> [E][C][R] bf16, both W1,W2 ----
__global__ __launch_bounds__(256) void transpose_both_kernel(
    const float* __restrict__ W1, const float* __restrict__ W2,
    u16* __restrict__ W1t, u16* __restrict__ W2t) {
  __shared__ u16 tile[64][72];
  int z = blockIdx.z;
  int e = z & 7;
  const float* s; u16* d; int R, C, c0, r0;
  if (z < NE) {
    s = W1 + (size_t)e * H * F; d = W1t + (size_t)e * H * F;
    R = H; C = F; c0 = blockIdx.x << 6; r0 = blockIdx.y << 6;
  } else {
    s = W2 + (size_t)e * F * H; d = W2t + (size_t)e * F * H;
    R = F; C = H; c0 = blockIdx.y << 6; r0 = blockIdx.x << 6;
  }
  int t = threadIdx.x;
  int rl = t >> 4, cl = (t & 15) << 2;
#pragma unroll
  for (int i = 0; i < 4; ++i) {
    float4 v = *reinterpret_cast<const float4*>(&s[(size_t)(r0 + rl + i * 16) * C + c0 + cl]);
    ushort4 o; o.x = f2bf(v.x); o.y = f2bf(v.y); o.z = f2bf(v.z); o.w = f2bf(v.w);
    *reinterpret_cast<ushort4*>(&tile[rl + i * 16][cl]) = o;
  }
  __syncthreads();
  int cl2 = t >> 4, rl2 = (t & 15) << 2;
#pragma unroll
  for (int i = 0; i < 4; ++i) {
    ushort4 o;
    o.x = tile[rl2 + 0][cl2 + i * 16];
    o.y = tile[rl2 + 1][cl2 + i * 16];
    o.z = tile[rl2 + 2][cl2 + i * 16];
    o.w = tile[rl2 + 3][cl2 + i * 16];
    *reinterpret_cast<ushort4*>(&d[(size_t)(c0 + cl2 + i * 16) * R + r0 + rl2]) = o;
  }
}

// ---------------- GEMM1: Hc = gelu(gather(Xb) @ W1t^T + b1) ----------------
// 2 LDS buffers + depth-2 counted vmcnt(4): per iter {wait, bar, ds+mfma, bar,
// stage it+2 into the buffer just freed}. LDS chunk-XOR swizzle: phys 16B chunk
// p of row r holds k-chunk p^((r>>1)&3) -> fragment reads spread 16 rows over
// all 8 bank-slots (2-way = free) instead of 8-way conflict at 64B row stride.
__global__ __launch_bounds__(256) void gemm1_kernel(
    const u16* __restrict__ Xb, const u16* __restrict__ W1t,
    const float* __restrict__ b1, const int* __restrict__ cnt,
    const int* __restrict__ off, const int* __restrict__ tok,
    u16* __restrict__ Hc) {
  int e = blockIdx.z;
  int n = cnt[e];
  int m0 = blockIdx.y << 7;
  if (m0 >= n) return;
  int n0 = blockIdx.x << 7;
  int rb = off[e];

  __shared__ alignas(16) u16 As[2][128 * 32];
  __shared__ alignas(16) u16 Bs[2][128 * 32];
  __shared__ int tokS[128];

  int tid = threadIdx.x;
  if (tid < 128) {
    int s = m0 + tid;
    tokS[tid] = (s < n) ? tok[e * T + s] : 0;
  }
  __syncthreads();

  // staging: linear LDS chunk c=tid covers (row=c>>2, phys chunk c&3); source
  // k-chunk is XOR-swizzled. Same value for the +256 half (row+64: xor is equal).
  int kchunk = (((tid & 3) ^ ((tid >> 3) & 3))) * 8;
  const u16* W1e = W1t + (size_t)e * F * H;
  const u16* aP0 = Xb + (size_t)tokS[tid >> 2] * H + kchunk;
  const u16* aP1 = Xb + (size_t)tokS[64 + (tid >> 2)] * H + kchunk;
  const u16* bP0 = W1e + (size_t)(n0 + (tid >> 2)) * H + kchunk;
  const u16* bP1 = W1e + (size_t)(n0 + 64 + (tid >> 2)) * H + kchunk;

  int wv = tid >> 6, lane = tid & 63;
  int wm = wv >> 1, wn = wv & 1;
  int quad = lane >> 4, l16 = lane & 15;

  floatx4 acc[4][4];
#pragma unroll
  for (int mt = 0; mt < 4; ++mt)
#pragma unroll
    for (int nt = 0; nt < 4; ++nt) acc[mt][nt] = floatx4{0.f, 0.f, 0.f, 0.f};

  // fragment read: row = base + i*16 + l16; xor(row) = (l16>>1)&3 (i*16,64*wm
  // vanish mod 4 after >>1); phys chunk = quad ^ xor.
  int qa = (quad ^ ((l16 >> 1) & 3)) * 8;
  int aOff[4], bOff[4];
#pragma unroll
  for (int i = 0; i < 4; ++i) {
    aOff[i] = (wm * 64 + i * 16 + l16) * 32 + qa;
    bOff[i] = (wn * 64 + i * 16 + l16) * 32 + qa;
  }

#define STAGE1(buf, kk)                                   \
  do {                                                    \
    load16_lds(aP0 + (kk), &As[buf][tid * 8]);            \
    load16_lds(aP1 + (kk), &As[buf][(tid + 256) * 8]);    \
    load16_lds(bP0 + (kk), &Bs[buf][tid * 8]);            \
    load16_lds(bP1 + (kk), &Bs[buf][(tid + 256) * 8]);    \
  } while (0)

  const int NIT = H / 32;  // 32
  STAGE1(0, 0);
  STAGE1(1, 32);
  for (int it = 0; it < NIT; ++it) {
    if (it >= NIT - 1) asm volatile("s_waitcnt vmcnt(0)" ::: "memory");
    else               asm volatile("s_waitcnt vmcnt(4)" ::: "memory");
    __builtin_amdgcn_s_barrier();
    int cur = it & 1;
    short8 av[4], bv[4];
#pragma unroll
    for (int i = 0; i < 4; ++i) {
      av[i] = *reinterpret_cast<const short8*>(&As[cur][aOff[i]]);
      bv[i] = *reinterpret_cast<const short8*>(&Bs[cur][bOff[i]]);
    }
#pragma unroll
    for (int mt = 0; mt < 4; ++mt)
#pragma unroll
      for (int nt = 0; nt < 4; ++nt)
        acc[mt][nt] = __builtin_amdgcn_mfma_f32_16x16x32_bf16(av[mt], bv[nt], acc[mt][nt], 0, 0, 0);
    __builtin_amdgcn_s_barrier();  // all waves done reading buf cur
    if (it + 2 < NIT) STAGE1(cur, (it + 2) * 32);  // refill freed buffer
  }
#undef STAGE1

  // epilogue: bias + gelu -> bf16 -> Hc[rb + row][col]
  float b1v[4];
#pragma unroll
  for (int nt = 0; nt < 4; ++nt)
    b1v[nt] = b1[e * F + n0 + wn * 64 + nt * 16 + l16];
#pragma unroll
  for (int mt = 0; mt < 4; ++mt) {
#pragma unroll
    for (int i = 0; i < 4; ++i) {
      int row = wm * 64 + mt * 16 + quad * 4 + i;
      int gr = m0 + row;
      if (gr < n) {
        u16* hrow = Hc + (size_t)(rb + gr) * F + n0 + wn * 64 + l16;
#pragma unroll
        for (int nt = 0; nt < 4; ++nt) {
          float v = acc[mt][nt][i] + b1v[nt];
          hrow[nt * 16] = f2bf(gelu_f(v));
        }
      }
    }
  }
}

// ---------------- GEMM2: out += w * (Hc @ W2t^T + b2) ----------------
// grid: (H/128, 32 m-tiles, NE*KSPLIT2). Same swizzle + depth-2 2-buffer pipe.
__global__ __launch_bounds__(256) void gemm2_kernel(
    const u16* __restrict__ Hc, const u16* __restrict__ W2t,
    const float* __restrict__ b2, const int* __restrict__ cnt,
    const int* __restrict__ off, const int* __restrict__ tok,
    const float* __restrict__ wgt, float* __restrict__ out) {
  int e = blockIdx.z >> 1;          // KSPLIT2 == 2
  int kc = blockIdx.z & 1;
  int n = cnt[e];
  int m0 = blockIdx.y << 7;
  if (m0 >= n) return;
  int n0 = blockIdx.x << 7;
  int rb = off[e];

  __shared__ alignas(16) u16 As[2][128 * 32];
  __shared__ alignas(16) u16 Bs[2][128 * 32];

  int tid = threadIdx.x;
  int kchunk = (((tid & 3) ^ ((tid >> 3) & 3))) * 8;
  const u16* W2e = W2t + (size_t)e * F * H;
  const u16* aP0 = Hc + (size_t)(rb + m0 + (tid >> 2)) * F + kchunk;
  const u16* aP1 = Hc + (size_t)(rb + m0 + 64 + (tid >> 2)) * F + kchunk;
  const u16* bP0 = W2e + (size_t)(n0 + (tid >> 2)) * F + kchunk;
  const u16* bP1 = W2e + (size_t)(n0 + 64 + (tid >> 2)) * F + kchunk;

  int wv = tid >> 6, lane = tid & 63;
  int wm = wv >> 1, wn = wv & 1;
  int quad = lane >> 4, l16 = lane & 15;

  floatx4 acc[4][4];
#pragma unroll
  for (int mt = 0; mt < 4; ++mt)
#pragma unroll
    for (int nt = 0; nt < 4; ++nt) acc[mt][nt] = floatx4{0.f, 0.f, 0.f, 0.f};

  int qa = (quad ^ ((l16 >> 1) & 3)) * 8;
  int aOff[4], bOff[4];
#pragma unroll
  for (int i = 0; i < 4; ++i) {
    aOff[i] = (wm * 64 + i * 16 + l16) * 32 + qa;
    bOff[i] = (wn * 64 + i * 16 + l16) * 32 + qa;
  }

#define STAGE2(buf, kk)                                   \
  do {                                                    \
    load16_lds(aP0 + (kk), &As[buf][tid * 8]);            \
    load16_lds(aP1 + (kk), &As[buf][(tid + 256) * 8]);    \
    load16_lds(bP0 + (kk), &Bs[buf][tid * 8]);            \
    load16_lds(bP1 + (kk), &Bs[buf][(tid + 256) * 8]);    \
  } while (0)

  const int kBeg = kc * (F / KSPLIT2);
  const int NIT = (F / KSPLIT2) / 32;  // 64
  STAGE2(0, kBeg);
  STAGE2(1, kBeg + 32);
  for (int it = 0; it < NIT; ++it) {
    if (it >= NIT - 1) asm volatile("s_waitcnt vmcnt(0)" ::: "memory");
    else               asm volatile("s_waitcnt vmcnt(4)" ::: "memory");
    __builtin_amdgcn_s_barrier();
    int cur = it & 1;
    short8 av[4], bv[4];
#pragma unroll
    for (int i = 0; i < 4; ++i) {
      av[i] = *reinterpret_cast<const short8*>(&As[cur][aOff[i]]);
      bv[i] = *reinterpret_cast<const short8*>(&Bs[cur][bOff[i]]);
    }
#pragma unroll
    for (int mt = 0; mt < 4; ++mt)
#pragma unroll
      for (int nt = 0; nt < 4; ++nt)
        acc[mt][nt] = __builtin_amdgcn_mfma_f32_16x16x32_bf16(av[mt], bv[nt], acc[mt][nt], 0, 0, 0);
    __builtin_amdgcn_s_barrier();
    if (it + 2 < NIT) STAGE2(cur, kBeg + (it + 2) * 32);
  }
#undef STAGE2

  float b2v[4];
#pragma unroll
  for (int nt = 0; nt < 4; ++nt)
    b2v[nt] = (kc == 0) ? b2[e * H + n0 + wn * 64 + nt * 16 + l16] : 0.0f;
#pragma unroll
  for (int mt = 0; mt < 4; ++mt) {
#pragma unroll
    for (int i = 0; i < 4; ++i) {
      int row = wm * 64 + mt * 16 + quad * 4 + i;
      int gr = m0 + row;
      if (gr < n) {
        float wv2 = wgt[e * T + gr];
        int tk = tok[e * T + gr];
        float* orow = out + (size_t)tk * H + n0 + wn * 64 + l16;
#pragma unroll
        for (int nt = 0; nt < 4; ++nt)
          atomicAdd(orow + nt * 16, (acc[mt][nt][i] + b2v[nt]) * wv2);
      }
    }
  }
}

extern "C" void kernel_launch(void* const* d_in, const int* in_sizes, int n_in,
                              void* d_out, int out_size, void* d_ws, size_t ws_size,
                              hipStream_t stream) {
  const float* x  = (const float*)d_in[0];
  const float* Wr = (const float*)d_in[1];
  const float* W1 = (const float*)d_in[2];
  const float* b1 = (const float*)d_in[3];
  const float* W2 = (const float*)d_in[4];
  const float* b2 = (const float*)d_in[5];
  float* out = (float*)d_out;

  char* ws = (char*)d_ws;
  // cnt@0 off@256 tok@4096(128K) wgt@135168(128K) Xb@266240(8M)
  // W1t@8654848(64M) W2t@75763712(64M) Hc@142872576(65M+slack) -> ~201MB total
  int*   cnt = (int*)(ws + 0);
  int*   off = (int*)(ws + 256);
  int*   tok = (int*)(ws + 4096);
  float* wgt = (float*)(ws + 135168);
  u16*   Xb  = (u16*)(ws + 266240);
  u16*   W1t = (u16*)(ws + 8654848);
  u16*   W2t = (u16*)(ws + 75763712);
  u16*   Hc  = (u16*)(ws + 142872576);

  hipMemsetAsync(cnt, 0, 64, stream);
  hipMemsetAsync(out, 0, (size_t)out_size * sizeof(float), stream);

  router_kernel<<<dim3(T / 4), dim3(256), 0, stream>>>(x, Wr, cnt, tok, wgt);
  offsets_kernel<<<dim3(1), dim3(64), 0, stream>>>(cnt, off);
  convert_x_kernel<<<dim3((T * H / 4) / 256), dim3(256), 0, stream>>>(x, Xb);
  transpose_both_kernel<<<dim3(64, 16, 16), dim3(256), 0, stream>>>(W1, W2, W1t, W2t);
  gemm1_kernel<<<dim3(F / 128, 32, NE), dim3(256), 0, stream>>>(Xb, W1t, b1, cnt, off, tok, Hc);
  gemm2_kernel<<<dim3(H / 128, 32, NE * KSPLIT2), dim3(256), 0, stream>>>(Hc, W2t, b2, cnt, off, tok, wgt, out);
}